// Round 12
// baseline (75.694 us; speedup 1.0000x reference)
//
#include <hip/hip_runtime.h>
#include <hip/hip_bf16.h>

typedef __attribute__((ext_vector_type(4))) float f32x4;
typedef __attribute__((ext_vector_type(8))) short bf16x8;

#define N_NEI 64
#define D_IN  128
#define D_HID 128

union BF8 { bf16x8 v; __hip_bfloat162 h[4]; unsigned u[4]; };

__device__ __forceinline__ unsigned bfbits(float f) {
  unsigned u = __float_as_uint(f);
  return (u + 0x7fffu + ((u >> 16) & 1u)) >> 16;  // RNE fp32->bf16
}

__device__ __forceinline__ bf16x8 pack8(const float4& a, const float4& b) {
  BF8 r;
  r.h[0] = __float22bfloat162_rn(float2{a.x, a.y});
  r.h[1] = __float22bfloat162_rn(float2{a.z, a.w});
  r.h[2] = __float22bfloat162_rn(float2{b.x, b.y});
  r.h[3] = __float22bfloat162_rn(float2{b.z, b.w});
  return r.v;
}

// Kernel 1 (cooperative DMA restructure): pooled[b][j] = max_n relu(neigh·W^T + b), masked n -> 0.
// Round-11 diagnosis: per-wave VGPR A-path is the structural binder — in-flight
// loads cost registers, so depth is capped and latency is serially exposed; five
// scheduling fixes were all noise. Fix: A-tiles staged via global_load_lds
// (zero VGPR cost in flight), block-cooperative:
//   block = 4 waves = 8 batch rows, grid 512 (2 blocks/CU, mutual stall-hiding)
//   step  = 32 neighbors of one row: 16KB contiguous -> LDS (16x1KB DMA, 4/wave)
//           +32B pad per 1KB chunk (A-frag reads 4-way instead of 16-way banks)
//   all 4 waves share the tile; wave w: 32 rows x cols [w*32, w*32+32)
//   2-phase dbuf: issue DMA(g+1) -> compute buf(g) -> barrier (T3-minimum)
// fp32 row-sums from LDS are exact -> mask semantics unchanged.
__global__ __launch_bounds__(256, 2)
void k1_pool(const float* __restrict__ neigh, const float* __restrict__ Wmlp,
             const float* __restrict__ bmlp, unsigned short* __restrict__ pooled) {
  __shared__ unsigned short Wl[D_HID * D_IN];  // 32KB bf16, swizzled
  __shared__ uint4 Abuf[2][1056];              // 2 x 16.5KB: 16 chunks x (1024B + 32B pad)

  const int tid = threadIdx.x;
  const int l = tid & 63;
  const int w = tid >> 6;
  const int lr = l & 15;   // A row-in-tile / B col-in-tile
  const int lg = l >> 4;   // k-group

  const char* nbase = (const char*)(neigh + (size_t)blockIdx.x * 8 * N_NEI * D_IN);

  // DMA step 0 first — flies under W staging
  #pragma unroll
  for (int i = 0; i < 4; ++i) {
    int c = w * 4 + i;
    __builtin_amdgcn_global_load_lds(
      (const __attribute__((address_space(1))) unsigned int*)(nbase + c * 1024 + l * 16),
      (__attribute__((address_space(3))) unsigned int*)((char*)Abuf[0] + c * 1056),
      16, 0, 0);
  }

  // stage W_mlp -> LDS bf16 (swizzled: byte = j*256 + ((d*2) ^ ((j&7)<<4)))
  const float4* W4 = (const float4*)Wmlp;
  #pragma unroll
  for (int it = 0; it < 8; ++it) {
    int f8 = it * 256 + tid;            // 8-float chunk id, 0..2047
    int j  = f8 >> 4;                   // row 0..127
    int d0 = (f8 & 15) * 8;             // col start
    float4 a = W4[f8 * 2];
    float4 bb = W4[f8 * 2 + 1];
    int byte = j * 256 + ((d0 * 2) ^ ((j & 7) << 4));
    *(bf16x8*)((char*)Wl + byte) = pack8(a, bb);
  }

  const float bml0 = bmlp[w * 32 + lr];
  const float bml1 = bmlp[w * 32 + 16 + lr];

  __syncthreads();   // drains W staging + DMA(0)

  float pmax0 = 0.f, pmax1 = 0.f;

  #pragma unroll 1
  for (int g = 0; g < 16; ++g) {        // 8 batch rows x 2 steps (32 neighbors each)
    const char* Ab = (const char*)Abuf[g & 1];

    // issue DMA for step g+1 (in flight under this step's compute)
    if (g < 15) {
      const char* src = nbase + (size_t)(g + 1) * 16384;
      char* dst = (char*)Abuf[(g + 1) & 1];
      #pragma unroll
      for (int i = 0; i < 4; ++i) {
        int c = w * 4 + i;
        __builtin_amdgcn_global_load_lds(
          (const __attribute__((address_space(1))) unsigned int*)(src + c * 1024 + l * 16),
          (__attribute__((address_space(3))) unsigned int*)(dst + c * 1056),
          16, 0, 0);
      }
    }

    // A fragments from LDS (fp32 -> bf16) + exact fp32 row-sums for the mask
    bf16x8 af[2][4];
    float rs0 = 0.f, rs1 = 0.f;
    #pragma unroll
    for (int mt = 0; mt < 2; ++mt) {
      #pragma unroll
      for (int ks = 0; ks < 4; ++ks) {
        int r = mt * 16 + lr;
        int addr = (r >> 1) * 1056 + (r & 1) * 512 + ks * 128 + lg * 32;
        float4 a0 = *(const float4*)(Ab + addr);
        float4 a1 = *(const float4*)(Ab + addr + 16);
        float s = a0.x + a0.y + a0.z + a0.w + a1.x + a1.y + a1.z + a1.w;
        if (mt == 0) rs0 += s; else rs1 += s;
        af[mt][ks] = pack8(a0, a1);
      }
    }
    rs0 += __shfl_xor(rs0, 16); rs0 += __shfl_xor(rs0, 32);
    rs1 += __shfl_xor(rs1, 16); rs1 += __shfl_xor(rs1, 32);
    unsigned mask0 = (unsigned)(__ballot(rs0 == 0.0f) & 0xFFFFull);
    unsigned mask1 = (unsigned)(__ballot(rs1 == 0.0f) & 0xFFFFull);

    // MFMA: 2 mtiles x 2 ntiles x 4 k; each W fragment read feeds both mtiles
    f32x4 acc[2][2];
    acc[0][0] = (f32x4){0.f, 0.f, 0.f, 0.f};
    acc[0][1] = (f32x4){0.f, 0.f, 0.f, 0.f};
    acc[1][0] = (f32x4){0.f, 0.f, 0.f, 0.f};
    acc[1][1] = (f32x4){0.f, 0.f, 0.f, 0.f};
    #pragma unroll
    for (int nt = 0; nt < 2; ++nt) {
      #pragma unroll
      for (int ks = 0; ks < 4; ++ks) {
        int jr = w * 32 + nt * 16 + lr;
        int d0 = ks * 32 + lg * 8;
        bf16x8 bf = *(const bf16x8*)((const char*)Wl + jr * 256 + ((d0 * 2) ^ ((jr & 7) << 4)));
        acc[0][nt] = __builtin_amdgcn_mfma_f32_16x16x32_bf16(af[0][ks], bf, acc[0][nt], 0, 0, 0);
        acc[1][nt] = __builtin_amdgcn_mfma_f32_16x16x32_bf16(af[1][ks], bf, acc[1][nt], 0, 0, 0);
      }
    }

    // relu + bias + mask, fold into running per-lane max (col = nt slice)
    #pragma unroll
    for (int mt = 0; mt < 2; ++mt) {
      unsigned m = mt ? mask1 : mask0;
      #pragma unroll
      for (int r = 0; r < 4; ++r) {
        int row = lg * 4 + r;            // D-layout: row = (l>>4)*4 + reg
        bool msk = (m >> row) & 1u;
        float v0 = fmaxf(acc[mt][0][r] + bml0, 0.f);
        float v1 = fmaxf(acc[mt][1][r] + bml1, 0.f);
        if (msk) { v0 = 0.f; v1 = 0.f; }
        pmax0 = fmaxf(pmax0, v0);
        pmax1 = fmaxf(pmax1, v1);
      }
    }

    // after both steps of a batch row: fold lg groups, store, reset
    if (g & 1) {
      float p0 = fmaxf(pmax0, __shfl_xor(pmax0, 16)); p0 = fmaxf(p0, __shfl_xor(p0, 32));
      float p1 = fmaxf(pmax1, __shfl_xor(pmax1, 16)); p1 = fmaxf(p1, __shfl_xor(p1, 32));
      if (lg == 0) {
        size_t bb = (size_t)blockIdx.x * 8 + (g >> 1);
        pooled[bb * D_HID + w * 32 + lr]      = (unsigned short)bfbits(p0);
        pooled[bb * D_HID + w * 32 + 16 + lr] = (unsigned short)bfbits(p1);
      }
      pmax0 = 0.f; pmax1 = 0.f;
    }

    __syncthreads();   // drains DMA(g+1); orders buf reuse
  }
}

// Kernel 2: out[b][j] = relu([input|pooled][b,:]·W_comb[j,:] + b_comb[j])
// Block = 64 rows x 64 cols (quarter of output cols), K = 256.  (round-8 verbatim)
__global__ __launch_bounds__(256, 2)
void k2_comb(const float* __restrict__ inp, const unsigned short* __restrict__ pooled,
             const float* __restrict__ Wcomb, const float* __restrict__ bcomb,
             float* __restrict__ out) {
  __shared__ unsigned short Wl[64 * 256];  // 32KB: 64 output cols x K=256, row = 512B, swizzled

  const int tid = threadIdx.x;
  const int l = tid & 63;
  const int w = tid >> 6;
  const int mchunk = blockIdx.x >> 2;   // 64-row chunk, 0..63
  const int colq   = blockIdx.x & 3;    // 64-col quarter
  const int lr = l & 15;
  const int lg = l >> 4;

  const int row = mchunk * 64 + w * 16 + lr;

  // 0. issue A loads first — overlap with W staging
  float4 a0[4], a1[4];
  #pragma unroll
  for (int ks = 0; ks < 4; ++ks) {   // k < 128: fp32 input
    const float* p = inp + (size_t)row * 128 + ks * 32 + lg * 8;
    a0[ks] = *(const float4*)p;
    a1[ks] = *(const float4*)(p + 4);
  }
  bf16x8 af[8];
  #pragma unroll
  for (int ks = 4; ks < 8; ++ks) {   // k >= 128: pooled already bf16
    af[ks] = *(const bf16x8*)(pooled + (size_t)row * 128 + (ks - 4) * 32 + lg * 8);
  }

  // 1. stage W quarter -> LDS bf16 (swizzled)
  const float4* W4 = (const float4*)Wcomb;
  #pragma unroll
  for (int it = 0; it < 8; ++it) {
    int c  = it * 256 + tid;            // 8-float chunk, 0..2047
    int jr = c >> 5;                    // 0..63
    int d0 = (c & 31) * 8;
    int gidx = ((colq * 64 + jr) * 256 + d0) >> 2;  // float4 index into W_comb
    float4 a = W4[gidx];
    float4 bb = W4[gidx + 1];
    int byte = jr * 512 + ((d0 * 2) ^ ((jr & 7) << 4));
    *(bf16x8*)((char*)Wl + byte) = pack8(a, bb);
  }

  float bcl[4];
  #pragma unroll
  for (int t = 0; t < 4; ++t) bcl[t] = bcomb[colq * 64 + t * 16 + lr];

  #pragma unroll
  for (int ks = 0; ks < 4; ++ks) af[ks] = pack8(a0[ks], a1[ks]);

  __syncthreads();

  f32x4 acc[4];
  #pragma unroll
  for (int t = 0; t < 4; ++t) acc[t] = (f32x4){0.f, 0.f, 0.f, 0.f};
  #pragma unroll
  for (int t = 0; t < 4; ++t) {
    #pragma unroll
    for (int ks = 0; ks < 8; ++ks) {
      int jr = t * 16 + lr;
      int d0 = ks * 32 + lg * 8;
      bf16x8 bf = *(const bf16x8*)((const char*)Wl + jr * 512 + ((d0 * 2) ^ ((jr & 7) << 4)));
      acc[t] = __builtin_amdgcn_mfma_f32_16x16x32_bf16(af[ks], bf, acc[t], 0, 0, 0);
    }
  }

  #pragma unroll
  for (int t = 0; t < 4; ++t) {
    #pragma unroll
    for (int r = 0; r < 4; ++r) {
      int ro = mchunk * 64 + w * 16 + lg * 4 + r;
      int co = colq * 64 + t * 16 + lr;
      float v = acc[t][r] + bcl[t];
      out[(size_t)ro * 256 + co] = fmaxf(v, 0.f);
    }
  }
}

extern "C" void kernel_launch(void* const* d_in, const int* in_sizes, int n_in,
                              void* d_out, int out_size, void* d_ws, size_t ws_size,
                              hipStream_t stream) {
  const float* inp   = (const float*)d_in[0];
  const float* neigh = (const float*)d_in[1];
  const float* Wmlp  = (const float*)d_in[2];
  const float* bmlp  = (const float*)d_in[3];
  const float* Wcomb = (const float*)d_in[4];
  const float* bcomb = (const float*)d_in[5];
  float* out = (float*)d_out;
  unsigned short* pooled = (unsigned short*)d_ws;  // [4096][128] bf16, 1 MB

  k1_pool<<<512, 256, 0, stream>>>(neigh, Wmlp, bmlp, pooled);
  k2_comb<<<256, 256, 0, stream>>>(inp, pooled, Wcomb, bcomb, out);
}

// Round 13
// 52.122 us; speedup vs baseline: 1.4522x; 1.4522x over previous
//
#include <hip/hip_runtime.h>
#include <hip/hip_bf16.h>

typedef __attribute__((ext_vector_type(4))) float f32x4;
typedef __attribute__((ext_vector_type(8))) short bf16x8;

#define N_NEI 64
#define D_IN  128
#define D_HID 128

union BF8 { bf16x8 v; __hip_bfloat162 h[4]; unsigned u[4]; };

__device__ __forceinline__ bf16x8 pack8(const float4& a, const float4& b) {
  BF8 r;
  r.h[0] = __float22bfloat162_rn(float2{a.x, a.y});
  r.h[1] = __float22bfloat162_rn(float2{a.z, a.w});
  r.h[2] = __float22bfloat162_rn(float2{b.x, b.y});
  r.h[3] = __float22bfloat162_rn(float2{b.z, b.w});
  return r.v;
}

// Kernel 1: pooled[b][j] = max_n relu(neigh[b,n,:]·W_mlp[j,:] + b_mlp[j]), masked rows -> 0.
// R8 structure verbatim (best measured, 36.75us): one block = 4 waves, each
// wave owns ONE batch row; DUAL M-TILE (32 rows/iter, every B-fragment LDS
// read feeds two MFMAs); pf[16] depth-1 prefetch; acc in 2 passes of 4.
// R12 counters: no spill at VGPR~88-160 band, FETCH 66MB (half L3-resident),
// latency/TLP-bound. Single change this round: launch_bounds (256,3) —
// cap 170 regs -> 3 blocks/CU (3 waves/SIMD, +50% TLP vs R8's 2) without
// the cap-128 spill R6 hit (demand ~160 <= 170).
__global__ __launch_bounds__(256, 3)
void k1_pool(const float* __restrict__ neigh, const float* __restrict__ Wmlp,
             const float* __restrict__ bmlp, unsigned short* __restrict__ pooled) {
  __shared__ unsigned short Wl[D_HID * D_IN];  // 32KB bf16, row j = 256B, XOR-swizzled
  __shared__ float pscr[4][D_HID];             // per-wave epilogue scratch

  const int tid = threadIdx.x;
  const int l = tid & 63;
  const int w = tid >> 6;
  const int lr = l & 15;   // A row-in-tile / B col-in-tile
  const int lg = l >> 4;   // k-group

  const int b = blockIdx.x * 4 + w;     // this wave's batch row
  const float* rowbase = neigh + (size_t)b * N_NEI * D_IN;

  // 0. issue iter-0's 32-row loads first — overlap with W staging below
  //    pf[0..7] = row lr, pf[8..15] = row lr+16
  float4 pf[16];
  {
    const float* ra = rowbase + (size_t)lr * D_IN + lg * 8;
    const float* rb = rowbase + (size_t)(16 + lr) * D_IN + lg * 8;
    #pragma unroll
    for (int ks = 0; ks < 4; ++ks) {
      pf[2 * ks]      = *(const float4*)(ra + ks * 32);
      pf[2 * ks + 1]  = *(const float4*)(ra + ks * 32 + 4);
      pf[8 + 2 * ks]  = *(const float4*)(rb + ks * 32);
      pf[9 + 2 * ks]  = *(const float4*)(rb + ks * 32 + 4);
    }
  }

  // 1. stage W_mlp -> LDS bf16 (swizzled: byte = j*256 + ((d*2) ^ ((j&7)<<4)))
  const float4* W4 = (const float4*)Wmlp;
  #pragma unroll
  for (int it = 0; it < 8; ++it) {
    int f8 = it * 256 + tid;            // 8-float chunk id, 0..2047
    int j  = f8 >> 4;                   // row 0..127
    int d0 = (f8 & 15) * 8;             // col start
    float4 a = W4[f8 * 2];
    float4 bb = W4[f8 * 2 + 1];
    int byte = j * 256 + ((d0 * 2) ^ ((j & 7) << 4));
    *(bf16x8*)((char*)Wl + byte) = pack8(a, bb);
  }

  float bml[8];
  #pragma unroll
  for (int t = 0; t < 8; ++t) bml[t] = bmlp[t * 16 + lr];

  __syncthreads();   // drains staging (and pf) — pf ready at loop entry

  float pmax[8];
  #pragma unroll
  for (int t = 0; t < 8; ++t) pmax[t] = 0.f;  // exact: masked entries are 0, relu >= 0

  #pragma unroll 1
  for (int it = 0; it < 2; ++it) {      // 32-neighbor dual M-tile per iteration
    // 2. consume pf: fp32->bf16 fragments + fp32 row-sums for the mask
    bf16x8 afA[4], afB[4];
    float rsA = 0.f, rsB = 0.f;
    #pragma unroll
    for (int ks = 0; ks < 4; ++ks) {
      float4 a0 = pf[2 * ks],     a1 = pf[2 * ks + 1];
      float4 b0 = pf[8 + 2 * ks], b1 = pf[9 + 2 * ks];
      rsA += a0.x + a0.y + a0.z + a0.w + a1.x + a1.y + a1.z + a1.w;
      rsB += b0.x + b0.y + b0.z + b0.w + b1.x + b1.y + b1.z + b1.w;
      afA[ks] = pack8(a0, a1);
      afB[ks] = pack8(b0, b1);
    }

    // 3. issue iter-1's loads — in flight under this iteration's MFMA section
    if (it == 0) {
      const float* ra = rowbase + (size_t)(32 + lr) * D_IN + lg * 8;
      const float* rb = rowbase + (size_t)(48 + lr) * D_IN + lg * 8;
      #pragma unroll
      for (int ks = 0; ks < 4; ++ks) {
        pf[2 * ks]      = *(const float4*)(ra + ks * 32);
        pf[2 * ks + 1]  = *(const float4*)(ra + ks * 32 + 4);
        pf[8 + 2 * ks]  = *(const float4*)(rb + ks * 32);
        pf[9 + 2 * ks]  = *(const float4*)(rb + ks * 32 + 4);
      }
    }

    rsA += __shfl_xor(rsA, 16); rsA += __shfl_xor(rsA, 32);
    rsB += __shfl_xor(rsB, 16); rsB += __shfl_xor(rsB, 32);
    unsigned maskA = (unsigned)(__ballot(rsA == 0.0f) & 0xFFFFull);
    unsigned maskB = (unsigned)(__ballot(rsB == 0.0f) & 0xFFFFull);

    // 4. two passes of 4 N-tiles; each B read feeds both M-tiles
    #pragma unroll 1
    for (int p = 0; p < 2; ++p) {
      f32x4 accA[4], accB[4];
      #pragma unroll
      for (int tt = 0; tt < 4; ++tt) {
        accA[tt] = (f32x4){0.f, 0.f, 0.f, 0.f};
        accB[tt] = (f32x4){0.f, 0.f, 0.f, 0.f};
      }

      #pragma unroll
      for (int tt = 0; tt < 4; ++tt) {
        #pragma unroll
        for (int ks = 0; ks < 4; ++ks) {
          int jr = (p * 4 + tt) * 16 + lr;
          int d0 = ks * 32 + lg * 8;
          bf16x8 bf = *(const bf16x8*)((const char*)Wl + jr * 256 + ((d0 * 2) ^ ((jr & 7) << 4)));
          accA[tt] = __builtin_amdgcn_mfma_f32_16x16x32_bf16(afA[ks], bf, accA[tt], 0, 0, 0);
          accB[tt] = __builtin_amdgcn_mfma_f32_16x16x32_bf16(afB[ks], bf, accB[tt], 0, 0, 0);
        }
      }

      // relu + bias + mask, fold into running per-lane max
      #pragma unroll
      for (int tt = 0; tt < 4; ++tt) {
        #pragma unroll
        for (int r = 0; r < 4; ++r) {
          int row = lg * 4 + r;          // D-layout: row = (l>>4)*4 + reg
          float vA = fmaxf(accA[tt][r] + bml[p * 4 + tt], 0.f);
          float vB = fmaxf(accB[tt][r] + bml[p * 4 + tt], 0.f);
          if ((maskA >> row) & 1u) vA = 0.f;
          if ((maskB >> row) & 1u) vB = 0.f;
          pmax[p * 4 + tt] = fmaxf(pmax[p * 4 + tt], fmaxf(vA, vB));
        }
      }
    }
  }

  // cross-lane-group max (rows live in lg groups)
  #pragma unroll
  for (int t = 0; t < 8; ++t) {
    pmax[t] = fmaxf(pmax[t], __shfl_xor(pmax[t], 16));
    pmax[t] = fmaxf(pmax[t], __shfl_xor(pmax[t], 32));
  }

  // epilogue: transpose via per-wave LDS scratch, packed bf16x2 store (256B/wave)
  if (l < 16) {
    #pragma unroll
    for (int t = 0; t < 8; ++t) pscr[w][t * 16 + l] = pmax[t];
  }
  __syncthreads();   // once per kernel; also orders pscr write->read
  float2 pv = *(const float2*)&pscr[w][2 * l];
  __hip_bfloat162 h2 = __float22bfloat162_rn(pv);
  ((unsigned*)(pooled + (size_t)b * D_HID))[l] = *(unsigned*)&h2;
}

// Kernel 2: out[b][j] = relu([input|pooled][b,:]·W_comb[j,:] + b_comb[j])
// Block = 64 rows x 64 cols (quarter of output cols), K = 256.  (R8 verbatim)
__global__ __launch_bounds__(256, 2)
void k2_comb(const float* __restrict__ inp, const unsigned short* __restrict__ pooled,
             const float* __restrict__ Wcomb, const float* __restrict__ bcomb,
             float* __restrict__ out) {
  __shared__ unsigned short Wl[64 * 256];  // 32KB: 64 output cols x K=256, row = 512B, swizzled

  const int tid = threadIdx.x;
  const int l = tid & 63;
  const int w = tid >> 6;
  const int mchunk = blockIdx.x >> 2;   // 64-row chunk, 0..63
  const int colq   = blockIdx.x & 3;    // 64-col quarter
  const int lr = l & 15;
  const int lg = l >> 4;

  const int row = mchunk * 64 + w * 16 + lr;

  // 0. issue A loads first — overlap with W staging
  float4 a0[4], a1[4];
  #pragma unroll
  for (int ks = 0; ks < 4; ++ks) {   // k < 128: fp32 input
    const float* p = inp + (size_t)row * 128 + ks * 32 + lg * 8;
    a0[ks] = *(const float4*)p;
    a1[ks] = *(const float4*)(p + 4);
  }
  bf16x8 af[8];
  #pragma unroll
  for (int ks = 4; ks < 8; ++ks) {   // k >= 128: pooled already bf16
    af[ks] = *(const bf16x8*)(pooled + (size_t)row * 128 + (ks - 4) * 32 + lg * 8);
  }

  // 1. stage W quarter -> LDS bf16 (swizzled)
  const float4* W4 = (const float4*)Wcomb;
  #pragma unroll
  for (int it = 0; it < 8; ++it) {
    int c  = it * 256 + tid;            // 8-float chunk, 0..2047
    int jr = c >> 5;                    // 0..63
    int d0 = (c & 31) * 8;
    int gidx = ((colq * 64 + jr) * 256 + d0) >> 2;  // float4 index into W_comb
    float4 a = W4[gidx];
    float4 bb = W4[gidx + 1];
    int byte = jr * 512 + ((d0 * 2) ^ ((jr & 7) << 4));
    *(bf16x8*)((char*)Wl + byte) = pack8(a, bb);
  }

  float bcl[4];
  #pragma unroll
  for (int t = 0; t < 4; ++t) bcl[t] = bcomb[colq * 64 + t * 16 + lr];

  #pragma unroll
  for (int ks = 0; ks < 4; ++ks) af[ks] = pack8(a0[ks], a1[ks]);

  __syncthreads();

  f32x4 acc[4];
  #pragma unroll
  for (int t = 0; t < 4; ++t) acc[t] = (f32x4){0.f, 0.f, 0.f, 0.f};
  #pragma unroll
  for (int t = 0; t < 4; ++t) {
    #pragma unroll
    for (int ks = 0; ks < 8; ++ks) {
      int jr = t * 16 + lr;
      int d0 = ks * 32 + lg * 8;
      bf16x8 bf = *(const bf16x8*)((const char*)Wl + jr * 512 + ((d0 * 2) ^ ((jr & 7) << 4)));
      acc[t] = __builtin_amdgcn_mfma_f32_16x16x32_bf16(af[ks], bf, acc[t], 0, 0, 0);
    }
  }

  #pragma unroll
  for (int t = 0; t < 4; ++t) {
    #pragma unroll
    for (int r = 0; r < 4; ++r) {
      int ro = mchunk * 64 + w * 16 + lg * 4 + r;
      int co = colq * 64 + t * 16 + lr;
      float v = acc[t][r] + bcl[t];
      out[(size_t)ro * 256 + co] = fmaxf(v, 0.f);
    }
  }
}

extern "C" void kernel_launch(void* const* d_in, const int* in_sizes, int n_in,
                              void* d_out, int out_size, void* d_ws, size_t ws_size,
                              hipStream_t stream) {
  const float* inp   = (const float*)d_in[0];
  const float* neigh = (const float*)d_in[1];
  const float* Wmlp  = (const float*)d_in[2];
  const float* bmlp  = (const float*)d_in[3];
  const float* Wcomb = (const float*)d_in[4];
  const float* bcomb = (const float*)d_in[5];
  float* out = (float*)d_out;
  unsigned short* pooled = (unsigned short*)d_ws;  // [4096][128] bf16, 1 MB

  k1_pool<<<1024, 256, 0, stream>>>(neigh, Wmlp, bmlp, pooled);
  k2_comb<<<256, 256, 0, stream>>>(inp, pooled, Wcomb, bcomb, out);
}